// Round 2
// baseline (1680.876 us; speedup 1.0000x reference)
//
#include <hip/hip_runtime.h>

#define NELEM  4
#define NMOL   64
#define NATOMS 16
#define ATOT   1024      // NMOL*NATOMS
#define REPD   256
#define NPCAS  128
#define DDIM   131072

// ---------------------------------------------------------------------------
// Kernel 0: stable counting-sort of atoms by element (molecule order preserved
// within each element group), compute group offsets, zero the output.
// Zidx staged in LDS so the serial pass is not HBM-latency-bound.
// ---------------------------------------------------------------------------
__global__ void k_sort(const int* __restrict__ Zidx, int* __restrict__ perm,
                       int* __restrict__ molid, int* __restrict__ goff,
                       float* __restrict__ out) {
    __shared__ int zl[ATOT];
    int t = threadIdx.x;
    for (int i = t; i < ATOT; i += blockDim.x) zl[i] = Zidx[i];
    __syncthreads();
    if (t == 0) {
        int cnt[NELEM] = {0, 0, 0, 0};
        for (int a = 0; a < ATOT; ++a) cnt[zl[a]]++;
        int off = 0;
        int pos[NELEM];
        for (int e = 0; e < NELEM; ++e) { goff[e] = off; pos[e] = off; off += cnt[e]; }
        goff[NELEM] = off;
        for (int a = 0; a < ATOT; ++a) {
            int e = zl[a];
            int p = pos[e]++;
            perm[p]  = a;
            molid[p] = a >> 4;   // a / NATOMS; atoms ascend -> mol-sorted in group
        }
    }
    if (t < NMOL) out[t] = 0.0f;
}

// ---------------------------------------------------------------------------
// Kernel 1: sub[i][p] = sum_r rep[a][r] * reductors[e][r][p], a = perm[i].
// rep[a][r] is wave-uniform -> scalar loads; reductor reads coalesce over p.
// ---------------------------------------------------------------------------
__global__ __launch_bounds__(NPCAS)
void k_sub(const float* __restrict__ rep, const float* __restrict__ red,
           const int* __restrict__ Zidx, const int* __restrict__ perm,
           float* __restrict__ sub) {
    int i = blockIdx.x;
    int p = threadIdx.x;
    int a = perm[i];            // uniform
    int e = Zidx[a];            // uniform
    const float* rp = rep + a * REPD;
    const float* wp = red + (size_t)(e * REPD) * NPCAS + p;
    float a0 = 0.f, a1 = 0.f, a2 = 0.f, a3 = 0.f;
    #pragma unroll 4
    for (int r = 0; r < REPD; r += 4) {
        a0 = fmaf(rp[r + 0], wp[(size_t)(r + 0) * NPCAS], a0);
        a1 = fmaf(rp[r + 1], wp[(size_t)(r + 1) * NPCAS], a1);
        a2 = fmaf(rp[r + 2], wp[(size_t)(r + 2) * NPCAS], a2);
        a3 = fmaf(rp[r + 3], wp[(size_t)(r + 3) * NPCAS], a3);
    }
    sub[i * NPCAS + p] = (a0 + a1) + (a2 + a3);
}

// ---------------------------------------------------------------------------
// Wave-reduce a per-lane value and accumulate into LDS outacc[m] (m uniform).
// ---------------------------------------------------------------------------
__device__ __forceinline__ void flush_partial(float val, int m, float* outacc) {
    #pragma unroll
    for (int s = 32; s >= 1; s >>= 1) val += __shfl_xor(val, s, 64);
    if ((threadIdx.x & 63) == 0) atomicAdd(&outacc[m], val);
}

// ---------------------------------------------------------------------------
// Kernel 2: main pass. Thread owns one column d. Per element: W column (128
// deep) into VGPRs (W read exactly once from HBM across the whole grid), then
// sweep that element's atoms; sub[j][*] wave-uniform -> scalar loads on the
// scalar pipe. 4 independent FMA chains for ILP. Per-mol running partial,
// flushed via wave shuffle reduce + LDS atomic; 64 global atomics per block.
// ---------------------------------------------------------------------------
__global__ __launch_bounds__(256)
void k_main(const float* __restrict__ W, const float* __restrict__ bvec,
            const float* __restrict__ alpha, const float* __restrict__ sub,
            const int* __restrict__ molid, const int* __restrict__ goff,
            float* __restrict__ out) {
    __shared__ float outacc[NMOL];
    int t = threadIdx.x;
    int d = blockIdx.x * 256 + t;
    if (t < NMOL) outacc[t] = 0.f;
    __syncthreads();

    // norm = sqrt(2/131072) = 1/256 exactly
    float scale = alpha[d] * 0.00390625f;
    float w[NPCAS];

    for (int e = 0; e < NELEM; ++e) {
        const float* Wp = W + (size_t)e * NPCAS * DDIM + d;
        #pragma unroll
        for (int p = 0; p < NPCAS; ++p) w[p] = Wp[(size_t)p * DDIM];
        float bias = bvec[e * DDIM + d];

        int j0 = goff[e], j1 = goff[e + 1];   // uniform scalar loads
        float cur = 0.f;
        int curmol = -1;
        for (int j = j0; j < j1; ++j) {
            int m = molid[j];                 // uniform
            if (m != curmol) {                // uniform branch
                if (curmol >= 0) flush_partial(cur * scale, curmol, outacc);
                cur = 0.f;
                curmol = m;
            }
            const float* sp = sub + j * NPCAS;   // uniform base -> s_loads
            float a0 = 0.f, a1 = 0.f, a2 = 0.f, a3 = 0.f;
            #pragma unroll
            for (int p = 0; p < NPCAS; p += 4) {
                a0 = fmaf(sp[p + 0], w[p + 0], a0);
                a1 = fmaf(sp[p + 1], w[p + 1], a1);
                a2 = fmaf(sp[p + 2], w[p + 2], a2);
                a3 = fmaf(sp[p + 3], w[p + 3], a3);
            }
            float acc = bias + ((a0 + a1) + (a2 + a3));
            cur += __cosf(acc);
        }
        if (curmol >= 0) flush_partial(cur * scale, curmol, outacc);
    }

    __syncthreads();
    if (t < NMOL) atomicAdd(&out[t], outacc[t]);
}

// ---------------------------------------------------------------------------
extern "C" void kernel_launch(void* const* d_in, const int* in_sizes, int n_in,
                              void* d_out, int out_size, void* d_ws, size_t ws_size,
                              hipStream_t stream) {
    const float* rep   = (const float*)d_in[0];   // [64,16,256]
    const float* red   = (const float*)d_in[1];   // [4,256,128]
    const float* W     = (const float*)d_in[2];   // [4,128,131072]
    const float* bvec  = (const float*)d_in[3];   // [4,131072]
    const float* alpha = (const float*)d_in[4];   // [131072]
    const int*   Zidx  = (const int*)d_in[5];     // [64,16]
    float* out = (float*)d_out;                   // [64]

    char* ws = (char*)d_ws;
    float* sub   = (float*)ws;                        // 1024*128*4 = 524288 B
    int*   perm  = (int*)(ws + 524288);               // 4096 B
    int*   molid = (int*)(ws + 524288 + 4096);        // 4096 B
    int*   goff  = (int*)(ws + 524288 + 8192);        // 20 B

    k_sort<<<1, 256, 0, stream>>>(Zidx, perm, molid, goff, out);
    k_sub<<<ATOT, NPCAS, 0, stream>>>(rep, red, Zidx, perm, sub);
    k_main<<<DDIM / 256, 256, 0, stream>>>(W, bvec, alpha, sub, molid, goff, out);
}